// Round 12
// baseline (220.813 us; speedup 1.0000x reference)
//
#include <hip/hip_runtime.h>
#include <hip/hip_bf16.h>

#define NN 100000
#define NE 1600000
#define NB 196            // dst-range buckets of 512 nodes
#define BCAP 9216         // padded bucket capacity (mean 8192, sd ~90 -> +11 sigma)
#define BIN_CHUNK 4096
#define BIN_BLKS ((NE + BIN_CHUNK - 1) / BIN_CHUNK)   // 391

typedef __attribute__((ext_vector_type(8))) short bf16x8;
typedef __attribute__((ext_vector_type(4))) float f32x4;

__device__ inline unsigned short f2bf(float f) {
    union { __hip_bfloat16 h; unsigned short u; } c;
    c.h = __float2bfloat16(f);
    return c.u;
}

// ---- fp8 e4m3fn encode (cold paths) ----------------------------------------
__device__ inline unsigned f2e4m3(float f) {
    unsigned u = __float_as_uint(f);
    unsigned s = (u >> 24) & 0x80u;
    unsigned b = u & 0x7FFFFFFFu;
    float af = __uint_as_float(b);
    if (af >= 464.f) return s | 0x7Eu;            // clamp to 448
    if (af < 0.015625f) {                          // e4m3 subnormal
        unsigned m = (unsigned)__float2int_rn(af * 512.f);
        return s | m;
    }
    unsigned r = b + 0x7FFFFu + ((b >> 20) & 1u);  // RNE to 3 mantissa bits
    int e = (int)(r >> 23) - 127;
    if (e > 8) return s | 0x7Eu;
    return s | ((unsigned)(e + 7) << 3) | ((r >> 20) & 7u);
}

// ---- fp8 e4m3fn decode (hot path) -------------------------------------------
#if __has_builtin(__builtin_amdgcn_cvt_f32_fp8)
#define FP8CVT(w, k) __builtin_amdgcn_cvt_f32_fp8((int)(w), (k))
#else
__device__ inline float fp8_manual(unsigned b) {
    unsigned v = ((b & 0x80u) << 24) | ((b & 0x7Fu) << 20);
    return __uint_as_float(v) * 0x1p120f;
}
#define FP8CVT(w, k) fp8_manual(((w) >> ((k) * 8)) & 0xFFu)
#endif

// ---- fused prep: gcur init + weight cvt + x -> bf16 + x -> fp8 --------------
__global__ __launch_bounds__(256) void k_prep(const float* __restrict__ x,
                                              unsigned short* __restrict__ xb,
                                              unsigned char* __restrict__ x8,
                                              const float* __restrict__ Wl1,
                                              const float* __restrict__ Wr1,
                                              const float* __restrict__ Wl2,
                                              const float* __restrict__ Wr2,
                                              unsigned short* __restrict__ Wc1,
                                              unsigned short* __restrict__ Wc2,
                                              int* __restrict__ gcur) {
    int i = blockIdx.x * 256 + threadIdx.x;
    if (i < NB) gcur[i] = i * BCAP;
    if (i < 4096) {
        int fo = i >> 6, k = i & 63;
        Wc1[fo * 128 + k]      = f2bf(Wl1[i]);
        Wc1[fo * 128 + 64 + k] = f2bf(Wr1[i]);
        Wc2[fo * 128 + k]      = f2bf(Wl2[i]);
        Wc2[fo * 128 + 64 + k] = f2bf(Wr2[i]);
    }
    if (i < NN * 64 / 8) {
        const float4* p = (const float4*)(x + (size_t)i * 8);
        float4 v0 = p[0], v1 = p[1];
        union { bf16x8 v; unsigned short u[8]; } c;
        c.u[0] = f2bf(v0.x); c.u[1] = f2bf(v0.y); c.u[2] = f2bf(v0.z); c.u[3] = f2bf(v0.w);
        c.u[4] = f2bf(v1.x); c.u[5] = f2bf(v1.y); c.u[6] = f2bf(v1.z); c.u[7] = f2bf(v1.w);
        *(bf16x8*)(xb + (size_t)i * 8) = c.v;
        unsigned lo = f2e4m3(v0.x) | (f2e4m3(v0.y) << 8) |
                      (f2e4m3(v0.z) << 16) | (f2e4m3(v0.w) << 24);
        unsigned hi = f2e4m3(v1.x) | (f2e4m3(v1.y) << 8) |
                      (f2e4m3(v1.z) << 16) | (f2e4m3(v1.w) << 24);
        *(uint2*)(x8 + (size_t)i * 8) = make_uint2(lo, hi);
    }
}

// ---- bin edges by dst>>9 into padded bucket regions (int4 vectorized) ------
__global__ __launch_bounds__(256) void k_bin(const int* __restrict__ src,
                                             const int* __restrict__ dst,
                                             int* __restrict__ gcur,
                                             unsigned* __restrict__ binned) {
    __shared__ int hist[NB];
    __shared__ int base[NB];
    __shared__ int lcur[NB];
    const int t = threadIdx.x;
    const int e0 = blockIdx.x * BIN_CHUNK;
    const int n4 = min(BIN_CHUNK, NE - e0) >> 2;
    for (int i = t; i < NB; i += 256) { hist[i] = 0; lcur[i] = 0; }
    __syncthreads();
    const int4* d4p = (const int4*)(dst + e0);
    const int4* s4p = (const int4*)(src + e0);
    for (int i = t; i < n4; i += 256) {
        int4 d = d4p[i];
        atomicAdd(&hist[d.x >> 9], 1);
        atomicAdd(&hist[d.y >> 9], 1);
        atomicAdd(&hist[d.z >> 9], 1);
        atomicAdd(&hist[d.w >> 9], 1);
    }
    __syncthreads();
    for (int i = t; i < NB; i += 256) {
        int h = hist[i];
        base[i] = h ? atomicAdd(&gcur[i], h) : 0;
    }
    __syncthreads();
    for (int i = t; i < n4; i += 256) {
        int4 d = d4p[i];
        int4 s = s4p[i];
        #define PLACE(dd, ss) {                                         \
            int b = (dd) >> 9;                                          \
            int p = base[b] + atomicAdd(&lcur[b], 1);                   \
            binned[p] = ((unsigned)((dd) & 511) << 17) | (unsigned)(ss);}
        PLACE(d.x, s.x) PLACE(d.y, s.y) PLACE(d.z, s.z) PLACE(d.w, s.w)
        #undef PLACE
    }
}

// ---- per-bucket CSR finalize -----------------------------------------------
__global__ __launch_bounds__(256) void k_csr(const int* __restrict__ gcur,
                                             unsigned* __restrict__ binned,
                                             int2* __restrict__ noff,
                                             float* __restrict__ inv) {
    __shared__ unsigned buf[BCAP];
    __shared__ int h[512];
    __shared__ int off[512];
    __shared__ int lcur[512];
    __shared__ int sc[256];
    const int b = blockIdx.x;
    const int t = threadIdx.x;
    const int base = b * BCAP;
    const int cnt = min(gcur[b] - base, BCAP);
    for (int i = t; i < 512; i += 256) h[i] = 0;
    __syncthreads();
    for (int i = t; i < cnt; i += 256) {
        unsigned v = binned[base + i];
        buf[i] = v;
        atomicAdd(&h[v >> 17], 1);
    }
    __syncthreads();
    int a0 = h[2 * t], a1 = h[2 * t + 1];
    sc[t] = a0 + a1;
    __syncthreads();
    #pragma unroll
    for (int o = 1; o < 256; o <<= 1) {
        int u = (t >= o) ? sc[t - o] : 0;
        __syncthreads();
        sc[t] += u;
        __syncthreads();
    }
    int ex = sc[t] - (a0 + a1);
    off[2 * t] = ex;          lcur[2 * t] = ex;
    off[2 * t + 1] = ex + a0; lcur[2 * t + 1] = ex + a0;
    __syncthreads();
    for (int i = t; i < cnt; i += 256) {
        unsigned v = buf[i];
        int dl = v >> 17;
        int p = atomicAdd(&lcur[dl], 1);
        binned[base + p] = v & 0x1FFFFu;
    }
    #pragma unroll
    for (int q = 0; q < 2; ++q) {
        int l = 2 * t + q;
        int node = b * 512 + l;
        if (node < NN) {
            int st = base + off[l];
            noff[node] = make_int2(st, st + h[l]);
            inv[node] = 1.0f / fmaxf((float)h[l], 1.0f);
        }
    }
}

// ---- Fused layer with BLOCK-BALANCED segmented aggregation ------------------
// The 64-node tile's edges are contiguous in binned[]. Each of 64 groups takes
// an equal chunk of ~E/64 edges; register-accumulates; flushes 8-float
// partials into an LDS f32 tile at node boundaries (~2 LDS atomics/lane/chunk).
// Then scale+convert -> bf16 sA tile -> 8-wave MFMA (self-path bf16 from feat).
__global__ __launch_bounds__(512) void k_fused(const unsigned short* __restrict__ feat,
                                               const unsigned char* __restrict__ f8,
                                               const int2* __restrict__ noff,
                                               const unsigned* __restrict__ csr,
                                               const float* __restrict__ inv,
                                               const unsigned short* __restrict__ Wc,
                                               const float* __restrict__ bias,
                                               float* __restrict__ Cf,
                                               unsigned short* __restrict__ Cb,
                                               unsigned char* __restrict__ C8) {
    __shared__ float accF[64 * 68];          // 17.4 KB (+4 f32 row pad)
    __shared__ int sEnds[64];
    __shared__ unsigned short sA[64 * 72];   // 9 KB
    const int t = threadIdx.x;
    const int n0 = blockIdx.x * 64;
    const int valid = min(64, NN - n0);

    if (t < 64) {
        int i = (t < valid) ? t : (valid - 1);
        sEnds[t] = noff[n0 + i].y;
    }
    for (int i = t; i < 64 * 68; i += 512) accF[i] = 0.f;
    __syncthreads();

    const int estart = noff[n0].x;
    const int eend = sEnds[63];
    const int E = eend - estart;

    // ---- phase 1: balanced segmented aggregation ----
    {
        const int g = t >> 3;        // group 0..63
        const int p = t & 7;         // feature octet
        const int cpg = (E + 63) >> 6;
        int gbeg = estart + g * cpg;
        int gend = min(gbeg + cpg, eend);
        if (gbeg < gend) {
            // first node i with gbeg < sEnds[i]
            int lo = 0, hi = 63;
            while (lo < hi) {
                int mid = (lo + hi) >> 1;
                if (gbeg < sEnds[mid]) hi = mid; else lo = mid + 1;
            }
            int cur = lo;
            int curEnd = sEnds[cur];
            float a[8] = {0.f, 0.f, 0.f, 0.f, 0.f, 0.f, 0.f, 0.f};

            #define FLUSH() {                                          \
                float* rp = accF + cur * 68 + p * 8;                   \
                atomicAdd(rp + 0, a[0]); atomicAdd(rp + 1, a[1]);      \
                atomicAdd(rp + 2, a[2]); atomicAdd(rp + 3, a[3]);      \
                atomicAdd(rp + 4, a[4]); atomicAdd(rp + 5, a[5]);      \
                atomicAdd(rp + 6, a[6]); atomicAdd(rp + 7, a[7]);      \
                a[0]=0.f;a[1]=0.f;a[2]=0.f;a[3]=0.f;                   \
                a[4]=0.f;a[5]=0.f;a[6]=0.f;a[7]=0.f; }
            #define PROC(jj, u) {                                      \
                while ((jj) >= curEnd) {                               \
                    FLUSH();                                           \
                    ++cur;                                             \
                    curEnd = sEnds[cur < 64 ? cur : 63];               \
                }                                                      \
                a[0] += FP8CVT((u).x, 0); a[1] += FP8CVT((u).x, 1);    \
                a[2] += FP8CVT((u).x, 2); a[3] += FP8CVT((u).x, 3);    \
                a[4] += FP8CVT((u).y, 0); a[5] += FP8CVT((u).y, 1);    \
                a[6] += FP8CVT((u).y, 2); a[7] += FP8CVT((u).y, 3); }
            #define GATHER(s) (*(const uint2*)(f8 + (size_t)(s) * 64 + p * 8))

            int j = gbeg;
            for (; j + 4 <= gend; j += 4) {
                uint2 q0 = GATHER(csr[j]);     uint2 q1 = GATHER(csr[j + 1]);
                uint2 q2 = GATHER(csr[j + 2]); uint2 q3 = GATHER(csr[j + 3]);
                PROC(j, q0) PROC(j + 1, q1) PROC(j + 2, q2) PROC(j + 3, q3)
            }
            for (; j < gend; ++j) {
                uint2 q = GATHER(csr[j]);
                PROC(j, q)
            }
            FLUSH();
            #undef GATHER
            #undef PROC
            #undef FLUSH
        }
    }
    __syncthreads();

    // ---- phase 1.5: scale by 1/deg, convert to bf16 tile ----
    {
        const int n = t >> 3;
        const int p = t & 7;
        const int node = n0 + n;
        float iv = (node < NN) ? inv[node] : 0.f;
        const float* rp = accF + n * 68 + p * 8;
        union { bf16x8 v; unsigned short u[8]; } c;
        #pragma unroll
        for (int e = 0; e < 8; ++e) c.u[e] = f2bf(rp[e] * iv);
        *(bf16x8*)(&sA[n * 72 + p * 8]) = c.v;
    }
    __syncthreads();

    // ---- phase 2: MFMA transform of the 64-node tile ----
    const int w = t >> 6;        // wave 0..7
    const int l = t & 63;
    const int cn = l & 15;       // A-row / B-col selector
    const int ks = l >> 4;       // k-subgroup
    const int s = w & 3;         // node strip (16 nodes)
    const int h = w >> 2;        // fo half (32 cols)
    const int lrow = s * 16 + cn;
    const int arow = n0 + lrow;
    const int aclamp = (arow < NN) ? arow : 0;

    f32x4 acc0 = {0.f, 0.f, 0.f, 0.f};
    f32x4 acc1 = {0.f, 0.f, 0.f, 0.f};

    #pragma unroll
    for (int kb = 0; kb < 4; ++kb) {
        bf16x8 aa;
        if (kb < 2) aa = *(const bf16x8*)(&sA[lrow * 72 + kb * 32 + ks * 8]);
        else        aa = *(const bf16x8*)(feat + (size_t)aclamp * 64 + (kb - 2) * 32 + ks * 8);
        const unsigned short* wb = Wc + cn * 128 + kb * 32 + ks * 8;
        bf16x8 b0 = *(const bf16x8*)(wb + (size_t)(2 * h) * 16 * 128);
        bf16x8 b1 = *(const bf16x8*)(wb + (size_t)(2 * h + 1) * 16 * 128);
        acc0 = __builtin_amdgcn_mfma_f32_16x16x32_bf16(aa, b0, acc0, 0, 0, 0);
        acc1 = __builtin_amdgcn_mfma_f32_16x16x32_bf16(aa, b1, acc1, 0, 0, 0);
    }

    // C/D layout: col = lane&15, row = (lane>>4)*4 + r
    #pragma unroll
    for (int fb = 0; fb < 2; ++fb) {
        f32x4 av = fb ? acc1 : acc0;
        int f = 2 * h + fb;
        float bv = bias[f * 16 + cn];
        #pragma unroll
        for (int r = 0; r < 4; ++r) {
            int node = n0 + s * 16 + ks * 4 + r;
            if (node < NN) {
                float val = av[r] + bv;
                if (Cb) {
                    Cb[(size_t)node * 64 + f * 16 + cn] = f2bf(val);
                    C8[(size_t)node * 64 + f * 16 + cn] = (unsigned char)f2e4m3(val);
                } else {
                    Cf[(size_t)node * 64 + f * 16 + cn] = val;
                }
            }
        }
    }
}

// ---- host ------------------------------------------------------------------

extern "C" void kernel_launch(void* const* d_in, const int* in_sizes, int n_in,
                              void* d_out, int out_size, void* d_ws, size_t ws_size,
                              hipStream_t stream) {
    const float* x   = (const float*)d_in[0];
    const int*   ei  = (const int*)d_in[1];
    const int*   src = ei;
    const int*   dst = ei + NE;
    const float* Wl1 = (const float*)d_in[2];
    const float* b1  = (const float*)d_in[3];
    const float* Wr1 = (const float*)d_in[4];
    const float* Wl2 = (const float*)d_in[5];
    const float* b2  = (const float*)d_in[6];
    const float* Wr2 = (const float*)d_in[7];
    float* out = (float*)d_out;

    char* ws = (char*)d_ws;
    size_t off = 0;
    auto alloc = [&](size_t bytes) {
        void* p = ws + off;
        off = (off + bytes + 255) & ~(size_t)255;
        return p;
    };
    unsigned short* xb     = (unsigned short*)alloc(2 * (size_t)NN * 64);   // 12.8 MB
    unsigned short* h1b    = (unsigned short*)alloc(2 * (size_t)NN * 64);   // 12.8 MB
    unsigned char*  x8     = (unsigned char*)alloc((size_t)NN * 64);        // 6.4 MB
    unsigned char*  h18    = (unsigned char*)alloc((size_t)NN * 64);        // 6.4 MB
    unsigned*       binned = (unsigned*)alloc(sizeof(unsigned) * NB * BCAP);// 7.2 MB
    int2*           noff   = (int2*)alloc(sizeof(int2) * NN);
    float*          inv    = (float*)alloc(sizeof(float) * NN);
    int*            gcur   = (int*)alloc(sizeof(int) * NB);
    unsigned short* Wc1    = (unsigned short*)alloc(2 * 64 * 128);
    unsigned short* Wc2    = (unsigned short*)alloc(2 * 64 * 128);

    // prep (gcur + weights + x->bf16 + x->fp8), then CSR build
    k_prep<<<(NN * 64 / 8 + 255) / 256, 256, 0, stream>>>(x, xb, x8, Wl1, Wr1, Wl2, Wr2,
                                                          Wc1, Wc2, gcur);
    k_bin <<<BIN_BLKS, 256, 0, stream>>>(src, dst, gcur, binned);
    k_csr <<<NB, 256, 0, stream>>>(gcur, binned, noff, inv);

    // layer 1: h1 (bf16 + fp8) = [agg(x8) | xb] @ Wc1^T + b1
    k_fused<<<(NN + 63) / 64, 512, 0, stream>>>(xb, x8, noff, binned, inv, Wc1, b1,
                                                (float*)nullptr, h1b, h18);
    // layer 2: out (f32) = [agg(h18) | h1b] @ Wc2^T + b2
    k_fused<<<(NN + 63) / 64, 512, 0, stream>>>(h1b, h18, noff, binned, inv, Wc2, b2,
                                                out, (unsigned short*)nullptr,
                                                (unsigned char*)nullptr);
}

// Round 13
// 140.826 us; speedup vs baseline: 1.5680x; 1.5680x over previous
//
#include <hip/hip_runtime.h>
#include <hip/hip_bf16.h>

#define NN 100000
#define NE 1600000
#define NB 196            // dst-range buckets of 512 nodes
#define BCAP 9216         // padded bucket capacity (mean 8192, sd ~90 -> +11 sigma)
#define BIN_CHUNK 8192
#define BIN_BLKS ((NE + BIN_CHUNK - 1) / BIN_CHUNK)   // 196

typedef __attribute__((ext_vector_type(8))) short bf16x8;
typedef __attribute__((ext_vector_type(4))) float f32x4;

__device__ inline unsigned short f2bf(float f) {
    union { __hip_bfloat16 h; unsigned short u; } c;
    c.h = __float2bfloat16(f);
    return c.u;
}

// ---- fused prep: gcur init + weight cvt + x cvt ----------------------------
__global__ __launch_bounds__(256) void k_prep(const float* __restrict__ x,
                                              unsigned short* __restrict__ xb,
                                              const float* __restrict__ Wl1,
                                              const float* __restrict__ Wr1,
                                              const float* __restrict__ Wl2,
                                              const float* __restrict__ Wr2,
                                              unsigned short* __restrict__ Wc1,
                                              unsigned short* __restrict__ Wc2,
                                              int* __restrict__ gcur) {
    int i = blockIdx.x * 256 + threadIdx.x;
    if (i < NB) gcur[i] = i * BCAP;
    if (i < 4096) {
        int fo = i >> 6, k = i & 63;
        Wc1[fo * 128 + k]      = f2bf(Wl1[i]);
        Wc1[fo * 128 + 64 + k] = f2bf(Wr1[i]);
        Wc2[fo * 128 + k]      = f2bf(Wl2[i]);
        Wc2[fo * 128 + 64 + k] = f2bf(Wr2[i]);
    }
    if (i < NN * 64 / 8) {
        const float4* p = (const float4*)(x + (size_t)i * 8);
        float4 v0 = p[0], v1 = p[1];
        union { bf16x8 v; unsigned short u[8]; } c;
        c.u[0] = f2bf(v0.x); c.u[1] = f2bf(v0.y); c.u[2] = f2bf(v0.z); c.u[3] = f2bf(v0.w);
        c.u[4] = f2bf(v1.x); c.u[5] = f2bf(v1.y); c.u[6] = f2bf(v1.z); c.u[7] = f2bf(v1.w);
        *(bf16x8*)(xb + (size_t)i * 8) = c.v;
    }
}

// ---- bin edges by dst>>9 into padded bucket regions (int4 vectorized) ------
__global__ __launch_bounds__(256) void k_bin(const int* __restrict__ src,
                                             const int* __restrict__ dst,
                                             int* __restrict__ gcur,
                                             unsigned* __restrict__ binned) {
    __shared__ int hist[NB];
    __shared__ int base[NB];
    __shared__ int lcur[NB];
    const int t = threadIdx.x;
    const int e0 = blockIdx.x * BIN_CHUNK;
    const int n4 = min(BIN_CHUNK, NE - e0) >> 2;    // always divisible by 4
    for (int i = t; i < NB; i += 256) { hist[i] = 0; lcur[i] = 0; }
    __syncthreads();
    const int4* d4p = (const int4*)(dst + e0);
    const int4* s4p = (const int4*)(src + e0);
    for (int i = t; i < n4; i += 256) {
        int4 d = d4p[i];
        atomicAdd(&hist[d.x >> 9], 1);
        atomicAdd(&hist[d.y >> 9], 1);
        atomicAdd(&hist[d.z >> 9], 1);
        atomicAdd(&hist[d.w >> 9], 1);
    }
    __syncthreads();
    for (int i = t; i < NB; i += 256) {
        int h = hist[i];
        base[i] = h ? atomicAdd(&gcur[i], h) : 0;
    }
    __syncthreads();
    for (int i = t; i < n4; i += 256) {
        int4 d = d4p[i];
        int4 s = s4p[i];
        #define PLACE(dd, ss) {                                         \
            int b = (dd) >> 9;                                          \
            int p = base[b] + atomicAdd(&lcur[b], 1);                   \
            binned[p] = ((unsigned)((dd) & 511) << 17) | (unsigned)(ss);}
        PLACE(d.x, s.x) PLACE(d.y, s.y) PLACE(d.z, s.z) PLACE(d.w, s.w)
        #undef PLACE
    }
}

// ---- per-bucket CSR finalize -----------------------------------------------
__global__ __launch_bounds__(256) void k_csr(const int* __restrict__ gcur,
                                             unsigned* __restrict__ binned,
                                             int2* __restrict__ noff,
                                             float* __restrict__ inv) {
    __shared__ unsigned buf[BCAP];
    __shared__ int h[512];
    __shared__ int off[512];
    __shared__ int lcur[512];
    __shared__ int s[256];
    const int b = blockIdx.x;
    const int t = threadIdx.x;
    const int base = b * BCAP;
    const int cnt = min(gcur[b] - base, BCAP);
    for (int i = t; i < 512; i += 256) h[i] = 0;
    __syncthreads();
    for (int i = t; i < cnt; i += 256) {
        unsigned v = binned[base + i];
        buf[i] = v;
        atomicAdd(&h[v >> 17], 1);
    }
    __syncthreads();
    int a0 = h[2 * t], a1 = h[2 * t + 1];
    s[t] = a0 + a1;
    __syncthreads();
    #pragma unroll
    for (int o = 1; o < 256; o <<= 1) {
        int u = (t >= o) ? s[t - o] : 0;
        __syncthreads();
        s[t] += u;
        __syncthreads();
    }
    int ex = s[t] - (a0 + a1);
    off[2 * t] = ex;          lcur[2 * t] = ex;
    off[2 * t + 1] = ex + a0; lcur[2 * t + 1] = ex + a0;
    __syncthreads();
    for (int i = t; i < cnt; i += 256) {
        unsigned v = buf[i];
        int dl = v >> 17;
        int p = atomicAdd(&lcur[dl], 1);
        binned[base + p] = v & 0x1FFFFu;
    }
    #pragma unroll
    for (int q = 0; q < 2; ++q) {
        int l = 2 * t + q;
        int node = b * 512 + l;
        if (node < NN) {
            int st = base + off[l];
            noff[node] = make_int2(st, st + h[l]);
            inv[node] = 1.0f / fmaxf((float)h[l], 1.0f);
        }
    }
}

// ---- Fused layer: aggregate 64-node tile (8 lanes/node, registers) to LDS,
//      then 8-wave MFMA transform; self-path read from the same feat table.
//      Phase-1 gather loop is software-pipelined: next 4-edge batch issued
//      before current batch unpacks -> ~8 uint4 in flight per group.
__global__ __launch_bounds__(512) void k_fused(const unsigned short* __restrict__ feat,
                                               const int2* __restrict__ noff,
                                               const unsigned* __restrict__ csr,
                                               const float* __restrict__ inv,
                                               const unsigned short* __restrict__ Wc,
                                               const float* __restrict__ bias,
                                               float* __restrict__ Cf,
                                               unsigned short* __restrict__ Cb) {
    __shared__ unsigned short sA[64 * 72];   // stride 72 shorts = 144 B (16B-mult)
    const int t = threadIdx.x;
    const int n0 = blockIdx.x * 64;

    // ---- phase 1: aggregation ----
    {
        const int g = t >> 3;        // local node 0..63
        const int p = t & 7;         // feature octet
        const int node = n0 + g;
        float a[8] = {0.f, 0.f, 0.f, 0.f, 0.f, 0.f, 0.f, 0.f};
        float iv = 0.f;
        if (node < NN) {
            int2 oe = noff[node];
            int beg = oe.x, end = oe.y;
            iv = inv[node];

            #define UNPK(uu, k)                                        \
                a[2*(k)]   += __uint_as_float((uu) << 16);             \
                a[2*(k)+1] += __uint_as_float((uu) & 0xffff0000u);
            #define UNPK4(q0, q1, q2, q3)                              \
                UNPK(q0.x, 0) UNPK(q0.y, 1) UNPK(q0.z, 2) UNPK(q0.w, 3)\
                UNPK(q1.x, 0) UNPK(q1.y, 1) UNPK(q1.z, 2) UNPK(q1.w, 3)\
                UNPK(q2.x, 0) UNPK(q2.y, 1) UNPK(q2.z, 2) UNPK(q2.w, 3)\
                UNPK(q3.x, 0) UNPK(q3.y, 1) UNPK(q3.z, 2) UNPK(q3.w, 3)
            #define GATHER(s) (*(const uint4*)(feat + (size_t)(s) * 64 + p * 8))

            int j = beg;
            uint4 u0, u1, u2, u3;
            bool pending = false;
            if (j + 4 <= end) {
                u0 = GATHER(csr[j]);     u1 = GATHER(csr[j + 1]);
                u2 = GATHER(csr[j + 2]); u3 = GATHER(csr[j + 3]);
                j += 4;
                pending = true;
            }
            for (; j + 4 <= end; j += 4) {
                uint4 v0 = GATHER(csr[j]);     uint4 v1 = GATHER(csr[j + 1]);
                uint4 v2 = GATHER(csr[j + 2]); uint4 v3 = GATHER(csr[j + 3]);
                UNPK4(u0, u1, u2, u3)
                u0 = v0; u1 = v1; u2 = v2; u3 = v3;
            }
            if (pending) { UNPK4(u0, u1, u2, u3) }
            for (; j < end; ++j) {
                uint4 w0 = GATHER(csr[j]);
                UNPK(w0.x, 0) UNPK(w0.y, 1) UNPK(w0.z, 2) UNPK(w0.w, 3)
            }
            #undef GATHER
            #undef UNPK4
            #undef UNPK
        }
        union { bf16x8 v; unsigned short u[8]; } c;
        #pragma unroll
        for (int e = 0; e < 8; ++e) c.u[e] = f2bf(a[e] * iv);
        *(bf16x8*)(&sA[g * 72 + p * 8]) = c.v;
    }
    __syncthreads();

    // ---- phase 2: MFMA transform of the 64-node tile ----
    const int w = t >> 6;        // wave 0..7
    const int l = t & 63;
    const int cn = l & 15;       // A-row / B-col selector
    const int ks = l >> 4;       // k-subgroup
    const int s = w & 3;         // node strip (16 nodes)
    const int h = w >> 2;        // fo half (32 cols)
    const int lrow = s * 16 + cn;
    const int arow = n0 + lrow;
    const int aclamp = (arow < NN) ? arow : 0;

    f32x4 acc0 = {0.f, 0.f, 0.f, 0.f};
    f32x4 acc1 = {0.f, 0.f, 0.f, 0.f};

    #pragma unroll
    for (int kb = 0; kb < 4; ++kb) {
        bf16x8 aa;
        if (kb < 2) aa = *(const bf16x8*)(&sA[lrow * 72 + kb * 32 + ks * 8]);
        else        aa = *(const bf16x8*)(feat + (size_t)aclamp * 64 + (kb - 2) * 32 + ks * 8);
        const unsigned short* wb = Wc + cn * 128 + kb * 32 + ks * 8;
        bf16x8 b0 = *(const bf16x8*)(wb + (size_t)(2 * h) * 16 * 128);
        bf16x8 b1 = *(const bf16x8*)(wb + (size_t)(2 * h + 1) * 16 * 128);
        acc0 = __builtin_amdgcn_mfma_f32_16x16x32_bf16(aa, b0, acc0, 0, 0, 0);
        acc1 = __builtin_amdgcn_mfma_f32_16x16x32_bf16(aa, b1, acc1, 0, 0, 0);
    }

    // C/D layout: col = lane&15, row = (lane>>4)*4 + r
    #pragma unroll
    for (int fb = 0; fb < 2; ++fb) {
        f32x4 av = fb ? acc1 : acc0;
        int f = 2 * h + fb;
        float bv = bias[f * 16 + cn];
        #pragma unroll
        for (int r = 0; r < 4; ++r) {
            int node = n0 + s * 16 + ks * 4 + r;
            if (node < NN) {
                float val = av[r] + bv;
                if (Cb) Cb[(size_t)node * 64 + f * 16 + cn] = f2bf(val);
                else    Cf[(size_t)node * 64 + f * 16 + cn] = val;
            }
        }
    }
}

// ---- host ------------------------------------------------------------------

extern "C" void kernel_launch(void* const* d_in, const int* in_sizes, int n_in,
                              void* d_out, int out_size, void* d_ws, size_t ws_size,
                              hipStream_t stream) {
    const float* x   = (const float*)d_in[0];
    const int*   ei  = (const int*)d_in[1];
    const int*   src = ei;
    const int*   dst = ei + NE;
    const float* Wl1 = (const float*)d_in[2];
    const float* b1  = (const float*)d_in[3];
    const float* Wr1 = (const float*)d_in[4];
    const float* Wl2 = (const float*)d_in[5];
    const float* b2  = (const float*)d_in[6];
    const float* Wr2 = (const float*)d_in[7];
    float* out = (float*)d_out;

    char* ws = (char*)d_ws;
    size_t off = 0;
    auto alloc = [&](size_t bytes) {
        void* p = ws + off;
        off = (off + bytes + 255) & ~(size_t)255;
        return p;
    };
    unsigned short* xb     = (unsigned short*)alloc(2 * (size_t)NN * 64);   // 12.8 MB
    unsigned short* h1b    = (unsigned short*)alloc(2 * (size_t)NN * 64);   // 12.8 MB
    unsigned*       binned = (unsigned*)alloc(sizeof(unsigned) * NB * BCAP);// 7.2 MB
    int2*           noff   = (int2*)alloc(sizeof(int2) * NN);
    float*          inv    = (float*)alloc(sizeof(float) * NN);
    int*            gcur   = (int*)alloc(sizeof(int) * NB);
    unsigned short* Wc1    = (unsigned short*)alloc(2 * 64 * 128);
    unsigned short* Wc2    = (unsigned short*)alloc(2 * 64 * 128);

    // prep (gcur + weights + x->bf16), then CSR build — reused by both layers
    k_prep<<<(NN * 64 / 8 + 255) / 256, 256, 0, stream>>>(x, xb, Wl1, Wr1, Wl2, Wr2,
                                                          Wc1, Wc2, gcur);
    k_bin <<<BIN_BLKS, 256, 0, stream>>>(src, dst, gcur, binned);
    k_csr <<<NB, 256, 0, stream>>>(gcur, binned, noff, inv);

    // layer 1: h1b (bf16) = [agg(xb) | xb] @ Wc1^T + b1
    k_fused<<<(NN + 63) / 64, 512, 0, stream>>>(xb, noff, binned, inv, Wc1, b1,
                                                (float*)nullptr, h1b);
    // layer 2: out (f32) = [agg(h1b) | h1b] @ Wc2^T + b2
    k_fused<<<(NN + 63) / 64, 512, 0, stream>>>(h1b, noff, binned, inv, Wc2, b2,
                                                out, (unsigned short*)nullptr);
}